// Round 4
// baseline (88.160 us; speedup 1.0000x reference)
//
#include <hip/hip_runtime.h>

// Analytic collapse (verified R1/R2, absmax 9.8e-4):
//   <Z_0> = prod_{j=1..7} cos(t_j+theta_j),  <Z_w> = prod_{j=0..w} cos(t_j+theta_j)
// Block = 16 consecutive tokens (2 octets) of one batch. Wave specialization:
// wave 0/1/2 hold Wq/Wk/Wv rows in 64 VGPRs (lane = out elem) and project all
// 16 tokens; x is read via readfirstlane-uniform addresses -> s_load (scalar
// cache). Wave 3 holds Wo and does the whole fused output GEMM (its phase-1
// idle mirrors waves 0-2's phase-3 idle; 2 co-resident blocks/CU overlap).

__device__ __forceinline__ int rfl(int v) { return __builtin_amdgcn_readfirstlane(v); }

// segmented (8-lane) product scan -> <Z_w>; j = lane&7
__device__ __forceinline__ float expect_z(float ang, int j, int lane) {
    const float c = cosf(ang);
    float d = (j == 0) ? 1.f : c;
    float s;
    s = __shfl_up(d, 1); if (j >= 1) d *= s;
    s = __shfl_up(d, 2); if (j >= 2) d *= s;
    s = __shfl_up(d, 4); if (j >= 4) d *= s;
    const float c0 = __shfl(c, lane & ~7);   // c at j=0
    const float pf = __shfl(d, lane | 7);    // prod c1..c7
    return (j == 0) ? pf : c0 * d;
}

__global__ __launch_bounds__(256)
void qattn_fused(const float* __restrict__ xg,
                 const float* __restrict__ wqg, const float* __restrict__ wkg,
                 const float* __restrict__ wvg, const float* __restrict__ wog,
                 const float* __restrict__ thg,
                 float* __restrict__ outg)
{
    __shared__ float sP[3][16][64];      // q,k,v expectations per token (12 KB)
    __shared__ float sScr[8][2][68];     // scrambled rows, padded (4.25 KB)

    const int tid  = threadIdx.x;
    const int lane = tid & 63;
    const int wg   = tid >> 6;
    const int b    = blockIdx.x >> 5;
    const int pr   = blockIdx.x & 31;    // token-pair-of-octets index
    const int s0   = pr * 16;            // first token in batch row
    const int sg0  = pr * 2;             // first octet index

    // ---- each wave loads its 64x64 W matrix into registers (lane = row e) ----
    const float* wm = (wg == 0) ? wqg : (wg == 1) ? wkg : (wg == 2) ? wvg : wog;
    float w[64];
    #pragma unroll
    for (int kc = 0; kc < 16; ++kc) {
        const float4 v = *(const float4*)(wm + lane * 64 + kc * 4);
        w[kc * 4 + 0] = v.x; w[kc * 4 + 1] = v.y;
        w[kc * 4 + 2] = v.z; w[kc * 4 + 3] = v.w;
    }
    const float thf = thg[lane & 7];
    const int j = lane & 7;

    // ---- phase 1: waves 0-2 project 16 tokens each; x via uniform s_loads ----
    if (wg < 3) {
        for (int t = 0; t < 16; ++t) {
            const float* xr = xg + (size_t)rfl((b * 512 + s0 + t) * 64);
            float a0 = 0.f, a1 = 0.f, a2 = 0.f, a3 = 0.f;  // 4-way chain split
            #pragma unroll
            for (int kc = 0; kc < 16; kc += 4) {
                const float4 x0 = *(const float4*)(xr + kc * 4);
                const float4 x1 = *(const float4*)(xr + kc * 4 + 4);
                const float4 x2 = *(const float4*)(xr + kc * 4 + 8);
                const float4 x3 = *(const float4*)(xr + kc * 4 + 12);
                a0 = fmaf(w[kc*4+ 0], x0.x, a0); a0 = fmaf(w[kc*4+ 1], x0.y, a0);
                a0 = fmaf(w[kc*4+ 2], x0.z, a0); a0 = fmaf(w[kc*4+ 3], x0.w, a0);
                a1 = fmaf(w[kc*4+ 4], x1.x, a1); a1 = fmaf(w[kc*4+ 5], x1.y, a1);
                a1 = fmaf(w[kc*4+ 6], x1.z, a1); a1 = fmaf(w[kc*4+ 7], x1.w, a1);
                a2 = fmaf(w[kc*4+ 8], x2.x, a2); a2 = fmaf(w[kc*4+ 9], x2.y, a2);
                a2 = fmaf(w[kc*4+10], x2.z, a2); a2 = fmaf(w[kc*4+11], x2.w, a2);
                a3 = fmaf(w[kc*4+12], x3.x, a3); a3 = fmaf(w[kc*4+13], x3.y, a3);
                a3 = fmaf(w[kc*4+14], x3.z, a3); a3 = fmaf(w[kc*4+15], x3.w, a3);
            }
            const float ang = ((a0 + a1) + (a2 + a3)) + thf;
            sP[wg][t][lane] = expect_z(ang, j, lane);
        }
    }
    __syncthreads();

    // ---- phase 2: per-token 8x8 head-mixing attention; 4 tokens per wave ----
    {
        const int i = lane >> 3;
        #pragma unroll
        for (int u = 0; u < 4; ++u) {
            const int t = wg * 4 + u;
            const float4 q0 = *(const float4*)&sP[0][t][i * 8];
            const float4 q1 = *(const float4*)&sP[0][t][i * 8 + 4];
            const float4 k0 = *(const float4*)&sP[1][t][j * 8];
            const float4 k1 = *(const float4*)&sP[1][t][j * 8 + 4];
            float sc = q0.x * k0.x;
            sc = fmaf(q0.y, k0.y, sc); sc = fmaf(q0.z, k0.z, sc);
            sc = fmaf(q0.w, k0.w, sc); sc = fmaf(q1.x, k1.x, sc);
            sc = fmaf(q1.y, k1.y, sc); sc = fmaf(q1.z, k1.z, sc);
            sc = fmaf(q1.w, k1.w, sc);
            sc *= 0.35355339059327373f;   // 1/sqrt(8)
            float m = sc;
            m = fmaxf(m, __shfl_xor(m, 1));
            m = fmaxf(m, __shfl_xor(m, 2));
            m = fmaxf(m, __shfl_xor(m, 4));
            const float ex = expf(sc - m);
            float sum = ex;
            sum += __shfl_xor(sum, 1);
            sum += __shfl_xor(sum, 2);
            sum += __shfl_xor(sum, 4);
            const float a = ex / sum;      // attn[t][i][j] at lane i*8+j
            float o = 0.f;                 // out[t][i][w], w = j
            #pragma unroll
            for (int jj = 0; jj < 8; ++jj) {
                const float ajj = __shfl(a, (lane & ~7) + jj);
                o = fmaf(ajj, sP[2][t][jj * 8 + j], o);
            }
            sScr[i][t >> 3][(t & 7) * 8 + j] = o;  // row h=i, col 8*(s&7)+w
        }
    }
    __syncthreads();

    // ---- phase 3: wave 3 computes all 16 output rows from register Wo ----
    if (wg == 3) {
        for (int ro = 0; ro < 16; ++ro) {
            const int h = ro >> 1, o = ro & 1;
            float y0 = 0.f, y1 = 0.f, y2 = 0.f, y3 = 0.f;
            #pragma unroll
            for (int kc = 0; kc < 16; kc += 4) {
                const float4 s0v = *(const float4*)&sScr[h][o][kc * 4];
                const float4 s1v = *(const float4*)&sScr[h][o][kc * 4 + 4];
                const float4 s2v = *(const float4*)&sScr[h][o][kc * 4 + 8];
                const float4 s3v = *(const float4*)&sScr[h][o][kc * 4 + 12];
                y0 = fmaf(w[kc*4+ 0], s0v.x, y0); y0 = fmaf(w[kc*4+ 1], s0v.y, y0);
                y0 = fmaf(w[kc*4+ 2], s0v.z, y0); y0 = fmaf(w[kc*4+ 3], s0v.w, y0);
                y1 = fmaf(w[kc*4+ 4], s1v.x, y1); y1 = fmaf(w[kc*4+ 5], s1v.y, y1);
                y1 = fmaf(w[kc*4+ 6], s1v.z, y1); y1 = fmaf(w[kc*4+ 7], s1v.w, y1);
                y2 = fmaf(w[kc*4+ 8], s2v.x, y2); y2 = fmaf(w[kc*4+ 9], s2v.y, y2);
                y2 = fmaf(w[kc*4+10], s2v.z, y2); y2 = fmaf(w[kc*4+11], s2v.w, y2);
                y3 = fmaf(w[kc*4+12], s3v.x, y3); y3 = fmaf(w[kc*4+13], s3v.y, y3);
                y3 = fmaf(w[kc*4+14], s3v.z, y3); y3 = fmaf(w[kc*4+15], s3v.w, y3);
            }
            const float y = (y0 + y1) + (y2 + y3);
            outg[(size_t)(b * 512 + h * 64 + sg0 + o) * 64 + lane] = y;
        }
    }
}

extern "C" void kernel_launch(void* const* d_in, const int* in_sizes, int n_in,
                              void* d_out, int out_size, void* d_ws, size_t ws_size,
                              hipStream_t stream) {
    const float* x  = (const float*)d_in[0];
    const float* wq = (const float*)d_in[1];
    const float* wk = (const float*)d_in[2];
    const float* wv = (const float*)d_in[3];
    const float* wo = (const float*)d_in[4];
    const float* th = (const float*)d_in[5];
    float* out = (float*)d_out;
    // B=16, S=512: 16 batches x 32 sixteen-token groups = 512 blocks
    qattn_fused<<<dim3(512), dim3(256), 0, stream>>>(x, wq, wk, wv, wo, th, out);
}